// Round 5
// baseline (215.606 us; speedup 1.0000x reference)
//
#include <hip/hip_runtime.h>

#define Bsz 8
#define Ssz 128
#define Dsz 512
#define D2 1024
#define Lsz 512
#define Rsz 50
#define SLOT 524288        // ushorts per slot (1 MB), all slots [b][m][l]
#define OUTMAT 131072

typedef __attribute__((ext_vector_type(8))) _Float16 f16x8;
typedef __attribute__((ext_vector_type(2))) __fp16 fp16x2;
typedef __attribute__((ext_vector_type(4))) float f32x4;

union UV4 { uint4 u; f16x8 h; };
union UH { unsigned short s; _Float16 h; };
union UP { fp16x2 h; unsigned u; };

struct K1Args {
  const float* W1[4];
  const float* b1[4];
};

__device__ __forceinline__ float f16lo(unsigned u) {
  UH x; x.s = (unsigned short)(u & 0xffffu); return (float)x.h;
}
__device__ __forceinline__ float f16hi(unsigned u) {
  UH x; x.s = (unsigned short)(u >> 16); return (float)x.h;
}
__device__ __forceinline__ unsigned pkrtz(float a, float b) {
  UP c; c.h = __builtin_amdgcn_cvt_pkrtz(a, b); return c.u;
}
__device__ __forceinline__ unsigned short f2h(float v) {
  UH x; x.h = (_Float16)v; return x.s;
}
__device__ __forceinline__ float rcpf(float x) {
  return __builtin_amdgcn_rcpf(x);
}

// tanh pair (packed across the feature dim): 1 - 2*rcp(ea*eb + 1).
// f16 overflow -> inf -> rcp 0 is the correct tanh limit.
__device__ __forceinline__ unsigned tanh2u(unsigned ea, unsigned eb) {
  UP a, b, p; a.u = ea; b.u = eb;
  const fp16x2 one = {(__fp16)1.0f, (__fp16)1.0f};
  p.h = a.h * b.h + one;
  const float h0 = fmaf(-2.0f, rcpf((float)p.h.x), 1.0f);
  const float h1 = fmaf(-2.0f, rcpf((float)p.h.y), 1.0f);
  return pkrtz(h0, h1);
}

// ---------------------------------------------------------------------------
// Prep (merged): z<4: W1[z] -> W1F f16 fragment order.
// z==4: x -> X16F f16 fragment order.
// z==5: x<16: label W2 -> W2F fragment order; x 16..18: Sums[h] = sum(w2_h)
//        + b2_h[0]; x 19..42: zero out[0 .. 3*OUTMAT) for pair atomics.
// ---------------------------------------------------------------------------
__global__ __launch_bounds__(256) void prep_all(
    const float* __restrict__ x, K1Args a, const float* __restrict__ W2,
    const float* __restrict__ w2a, const float* __restrict__ w2b,
    const float* __restrict__ w2c,
    const float* __restrict__ b2a, const float* __restrict__ b2b,
    const float* __restrict__ b2c,
    unsigned short* __restrict__ W1F, unsigned short* __restrict__ X16F,
    unsigned short* __restrict__ W2F, float* __restrict__ Sums,
    float* __restrict__ out) {
  const int z = blockIdx.z;
  const int t = threadIdx.x;
  if (z < 4) {
    if (blockIdx.x >= 8) return;
    __shared__ float S[64][65];
    const float* __restrict__ W = a.W1[z];
    const int n0 = blockIdx.x * 64;
    const int k0 = blockIdx.y * 64;
    {
      const int kk = t >> 2, c16 = (t & 3) * 16;
      const float* p = W + (k0 + kk) * Lsz + n0 + c16;
#pragma unroll
      for (int c = 0; c < 4; ++c) {
        float4 v = *(const float4*)(p + c * 4);
        S[kk][c16 + c * 4 + 0] = v.x; S[kk][c16 + c * 4 + 1] = v.y;
        S[kk][c16 + c * 4 + 2] = v.z; S[kk][c16 + c * 4 + 3] = v.w;
      }
    }
    __syncthreads();
#pragma unroll
    for (int o = t; o < 512; o += 256) {
      const int lane = o & 63;
      const int ntl = (o >> 6) & 3, kbl = o >> 8;
      const int n_l = ntl * 16 + (lane & 15);
      const int k_l = kbl * 32 + (lane >> 4) * 8;
      uint4 pk;
      pk.x = pkrtz(S[k_l + 0][n_l], S[k_l + 1][n_l]);
      pk.y = pkrtz(S[k_l + 2][n_l], S[k_l + 3][n_l]);
      pk.z = pkrtz(S[k_l + 4][n_l], S[k_l + 5][n_l]);
      pk.w = pkrtz(S[k_l + 6][n_l], S[k_l + 7][n_l]);
      const long addr =
          ((long)((z * 32 + blockIdx.x * 4 + ntl) * 32 + blockIdx.y * 2 + kbl) *
               64 + lane) * 8;
      *(uint4*)(W1F + addr) = pk;
    }
  } else if (z == 4) {
    if (blockIdx.x >= 16) return;
    const int idx = (blockIdx.y * 16 + blockIdx.x) * 256 + t;  // [0,65536)
    const int frag = idx >> 6, lane = idx & 63;
    const int m = (frag >> 4) * 16 + (lane & 15);
    const int k0 = (frag & 15) * 32 + (lane >> 4) * 8;
    const float* p = x + m * Dsz + k0;
    float4 v0 = *(const float4*)p, v1 = *(const float4*)(p + 4);
    uint4 pk = make_uint4(pkrtz(v0.x, v0.y), pkrtz(v0.z, v0.w),
                          pkrtz(v1.x, v1.y), pkrtz(v1.z, v1.w));
    *(uint4*)(X16F + (long)idx * 8) = pk;
  } else {
    if (blockIdx.y != 0) return;
    if (blockIdx.x < 16) {
      const int idx = blockIdx.x * 256 + t;  // [0,4096)
      const int frag = idx >> 6, lane = idx & 63;
      const int o = (frag >> 4) * 16 + (lane & 15);
      const int k0 = (frag & 15) * 32 + (lane >> 4) * 8;
      float v[8];
#pragma unroll
      for (int e = 0; e < 8; ++e)
        v[e] = (o < Rsz) ? W2[(k0 + e) * Rsz + o] : 0.0f;
      uint4 pk = make_uint4(pkrtz(v[0], v[1]), pkrtz(v[2], v[3]),
                            pkrtz(v[4], v[5]), pkrtz(v[6], v[7]));
      *(uint4*)(W2F + (long)idx * 8) = pk;
    } else if (blockIdx.x < 19) {
      const int h = blockIdx.x - 16;
      const float* __restrict__ w2 = (h == 0) ? w2a : (h == 1 ? w2b : w2c);
      const float bb = (h == 0) ? b2a[0] : (h == 1 ? b2b[0] : b2c[0]);
      __shared__ float red[256];
      red[t] = w2[t] + w2[t + 256];
      __syncthreads();
      for (int s = 128; s > 0; s >>= 1) {
        if (t < s) red[t] += red[t + s];
        __syncthreads();
      }
      if (t == 0) Sums[h] = red[0] + bb;
    } else if (blockIdx.x < 43) {
      // zero the 3 scalar-head output matrices (atomicAdd targets)
      const int zb = blockIdx.x - 19;           // 0..23
      float* base = out + zb * 16384;
      const float4 zz = make_float4(0.f, 0.f, 0.f, 0.f);
#pragma unroll
      for (int k = 0; k < 16; ++k)
        *(float4*)(base + k * 1024 + t * 4) = zz;
    }
  }
}

// ---------------------------------------------------------------------------
// Kernel 1: projections, pure f16 MFMA, all K-loop loads coalesced (fragment
// order). Block 64m x 64n, wave 32x32, K=512 (side r = k-half of W1F).
// Epilogue: e = exp(2*(v + b1[left only])) stored f16 row-major [b][m][l]
// for ALL 8 slots.
// ---------------------------------------------------------------------------
__global__ __launch_bounds__(256) void gemm_lr_f16f(
    const unsigned short* __restrict__ X16F,
    const unsigned short* __restrict__ W1F, K1Args a,
    unsigned short* __restrict__ U) {
  const int side = blockIdx.z;
  const int h = side >> 1, r = side & 1;
  const float* __restrict__ bias = a.b1[h];
  const int tid = threadIdx.x;
  const int w = tid >> 6, lane = tid & 63;
  const int lm = lane & 15, q = lane >> 4;
  const int mtb = blockIdx.y * 4 + (w & 1) * 2;   // m-tile base (of 16)
  const int ntb = blockIdx.x * 4 + (w >> 1) * 2;  // n-tile base

  f32x4 acc[2][2];
#pragma unroll
  for (int mt = 0; mt < 2; ++mt)
#pragma unroll
    for (int nt = 0; nt < 2; ++nt) {
      acc[mt][nt].x = 0.f; acc[mt][nt].y = 0.f;
      acc[mt][nt].z = 0.f; acc[mt][nt].w = 0.f;
    }

  for (int kb = 0; kb < 16; ++kb) {
    UV4 af[2], bf[2];
#pragma unroll
    for (int mt = 0; mt < 2; ++mt)
      af[mt].u = *(const uint4*)(X16F +
          ((long)((mtb + mt) * 16 + kb) * 64 + lane) * 8);
#pragma unroll
    for (int nt = 0; nt < 2; ++nt)
      bf[nt].u = *(const uint4*)(W1F +
          ((long)((h * 32 + ntb + nt) * 32 + r * 16 + kb) * 64 + lane) * 8);
#pragma unroll
    for (int mt = 0; mt < 2; ++mt)
#pragma unroll
      for (int nt = 0; nt < 2; ++nt)
        acc[mt][nt] = __builtin_amdgcn_mfma_f32_16x16x32_f16(
            af[mt].h, bf[nt].h, acc[mt][nt], 0, 0, 0);
  }

  unsigned short* slot = U + side * SLOT;
#pragma unroll
  for (int nt = 0; nt < 2; ++nt) {
    const int n_out = (ntb + nt) * 16 + lm;
    const float bb = (r == 0) ? bias[n_out] : 0.0f;
#pragma unroll
    for (int mt = 0; mt < 2; ++mt) {
#pragma unroll
      for (int reg = 0; reg < 4; ++reg) {
        const int m_out = (mtb + mt) * 16 + q * 4 + reg;
        float v;
        if (reg == 0) v = acc[mt][nt].x;
        else if (reg == 1) v = acc[mt][nt].y;
        else if (reg == 2) v = acc[mt][nt].z;
        else v = acc[mt][nt].w;
        slot[m_out * Lsz + n_out] = f2h(__expf(2.0f * (v + bb)));
      }
    }
  }
}

// ---------------------------------------------------------------------------
// Fused pair kernel v5: uniform ~256-sigma/thread blocks for load balance.
// Grid x in [0,512) per b, 1:3 interleave:
//   (x&3)==0 -> label block, i = x>>2 (128 per b), v2 global-direct MFMA path.
//   else     -> scalar block s = (x>>2)*3 + (x&3) - 1 in [0,384):
//                t6 = s>>2 (96 tiles: h=t6>>5, it, jt), lq = s&3 (l-quarter).
// Scalar blocks compute a 128-l partial of the 16i x 32j tile and combine
// via device-scope atomicAdd into the prep-zeroed output (Sums added by
// the lq==0 block). Span (h==0): skip tiles above diagonal; strict-mirror.
// ---------------------------------------------------------------------------
__global__ __launch_bounds__(256) void pair_fused(
    const unsigned short* __restrict__ U,
    const unsigned short* __restrict__ W2F,
    const float* __restrict__ b2l,
    const float* __restrict__ w2a, const float* __restrict__ w2b,
    const float* __restrict__ w2c, const float* __restrict__ Sums,
    float* __restrict__ out) {
  __shared__ unsigned short As[16][66];   // [i][l], pitch 66: 4B-aligned rows,
  __shared__ unsigned short Bs[32][66];   //   conflict-free column reads
  __shared__ float w2s[64];

  const int b = blockIdx.y;
  const int tid = threadIdx.x;
  const int xr = blockIdx.x & 3;

  if (xr == 0) {
    // ----------------------- label head (global-direct) -------------------
    const int i = blockIdx.x >> 2;
    const int w = tid >> 6, lane = tid & 63;
    const int lm = lane & 15, q = lane >> 4;
    const int jb = w * 32;

    const unsigned short* __restrict__ Lrow =
        U + 6 * SLOT + (b * Ssz + i) * Lsz;
    const unsigned short* __restrict__ Rb0 = U + 7 * SLOT + (long)b * Ssz * Lsz;
    float* out3 = out + 3 * OUTMAT;

    const unsigned short* Lb = Lrow + q * 8;
    const unsigned short* R0 = Rb0 + (jb + lm) * Lsz + q * 8;        // mt=0
    const unsigned short* R1 = Rb0 + (jb + 16 + lm) * Lsz + q * 8;   // mt=1
    const unsigned short* Bb = W2F + lane * 8;

    f32x4 acc[2][4];
#pragma unroll
    for (int mt = 0; mt < 2; ++mt)
#pragma unroll
      for (int nt = 0; nt < 4; ++nt) {
        acc[mt][nt].x = 0.f; acc[mt][nt].y = 0.f;
        acc[mt][nt].z = 0.f; acc[mt][nt].w = 0.f;
      }

#pragma unroll 2
    for (int c = 0; c < 8; ++c) {
      const uint4 lf0 = *(const uint4*)(Lb + c * 64);
      const uint4 lf1 = *(const uint4*)(Lb + c * 64 + 32);
#pragma unroll
      for (int kbl = 0; kbl < 2; ++kbl) {
        const uint4 lf = kbl ? lf1 : lf0;
        UV4 bfr[4];
#pragma unroll
        for (int nt = 0; nt < 4; ++nt)
          bfr[nt].u =
              *(const uint4*)(Bb + (long)(nt * 16 + kbl + 2 * c) * 512);
#pragma unroll
        for (int mt = 0; mt < 2; ++mt) {
          const uint4 rv =
              *(const uint4*)((mt ? R1 : R0) + c * 64 + kbl * 32);
          UV4 A;
          A.u = make_uint4(tanh2u(lf.x, rv.x), tanh2u(lf.y, rv.y),
                           tanh2u(lf.z, rv.z), tanh2u(lf.w, rv.w));
#pragma unroll
          for (int nt = 0; nt < 4; ++nt)
            acc[mt][nt] = __builtin_amdgcn_mfma_f32_16x16x32_f16(
                A.h, bfr[nt].h, acc[mt][nt], 0, 0, 0);
        }
      }
    }

#pragma unroll
    for (int nt = 0; nt < 4; ++nt) {
      const int o = nt * 16 + lm;
      if (o >= Rsz) continue;
      const float bias = b2l[o];
#pragma unroll
      for (int mt = 0; mt < 2; ++mt) {
#pragma unroll
        for (int reg = 0; reg < 4; ++reg) {
          const int j = jb + mt * 16 + q * 4 + reg;
          const long base = ((long)((b * Ssz + i) * Ssz) + j) * Rsz;
          float v;
          if (reg == 0) v = acc[mt][nt].x;
          else if (reg == 1) v = acc[mt][nt].y;
          else if (reg == 2) v = acc[mt][nt].z;
          else v = acc[mt][nt].w;
          out3[base + o] = v + bias;
        }
      }
    }
  } else {
    // -------------------- scalar heads (l-quarter partials) ---------------
    const int s = (blockIdx.x >> 2) * 3 + xr - 1;   // [0, 384)
    const int t6 = s >> 2, lq = s & 3;
    const int h = t6 >> 5;
    const int r = t6 & 31;
    const int it = r >> 2, jt = r & 3;
    const int i0 = it * 16, j0 = jt * 32;
    if (h == 0 && i0 + 15 < j0) return;   // span: tile fully above diagonal
    const int t = tid;
    const int tj = t & 31;        // j offset
    const int th2 = (t >> 5) * 2; // i offset (pair)

    const unsigned short* __restrict__ A =
        U + (2 * h) * SLOT + (long)(b * Ssz + i0) * Lsz;
    const unsigned short* __restrict__ Bt =
        U + (2 * h + 1) * SLOT + (long)(b * Ssz + j0) * Lsz;
    const float* __restrict__ w2 = (h == 0) ? w2a : (h == 1 ? w2b : w2c);
    const int lb = lq * 128;

    // staging coords: row = t>>3, c8 = (t&7)*8
    const int srow = t >> 3;
    const int sc8 = (t & 7) * 8;

    float accE0 = 0.f, accO0 = 0.f, accE1 = 0.f, accO1 = 0.f;

    for (int c = 0; c < 2; ++c) {
      const int lo = lb + c * 64;
      __syncthreads();
      if (t < 128) {
        const uint4 ra = *(const uint4*)(A + srow * Lsz + lo + sc8);
        *(unsigned*)&As[srow][sc8 + 0] = ra.x;
        *(unsigned*)&As[srow][sc8 + 2] = ra.y;
        *(unsigned*)&As[srow][sc8 + 4] = ra.z;
        *(unsigned*)&As[srow][sc8 + 6] = ra.w;
      }
      {
        const uint4 rb = *(const uint4*)(Bt + srow * Lsz + lo + sc8);
        *(unsigned*)&Bs[srow][sc8 + 0] = rb.x;
        *(unsigned*)&Bs[srow][sc8 + 2] = rb.y;
        *(unsigned*)&Bs[srow][sc8 + 4] = rb.z;
        *(unsigned*)&Bs[srow][sc8 + 6] = rb.w;
      }
      if (t < 64) w2s[t] = w2[lo + t];
      __syncthreads();
#pragma unroll 4
      for (int l = 0; l < 64; l += 2) {
        const unsigned ua0 = *(const unsigned*)&As[th2][l];
        const unsigned ua1 = *(const unsigned*)&As[th2 + 1][l];
        const unsigned ub  = *(const unsigned*)&Bs[tj][l];
        const float2 wv = *(const float2*)&w2s[l];
        const float b0 = f16lo(ub), b1 = f16hi(ub);
        accE0 = fmaf(wv.x, rcpf(fmaf(f16lo(ua0), b0, 1.0f)), accE0);
        accO0 = fmaf(wv.y, rcpf(fmaf(f16hi(ua0), b1, 1.0f)), accO0);
        accE1 = fmaf(wv.x, rcpf(fmaf(f16lo(ua1), b0, 1.0f)), accE1);
        accO1 = fmaf(wv.y, rcpf(fmaf(f16hi(ua1), b1, 1.0f)), accO1);
      }
    }

    const float base = (lq == 0) ? Sums[h] : 0.0f;
    const float v0 = fmaf(-2.0f, accE0 + accO0, base);
    const float v1 = fmaf(-2.0f, accE1 + accO1, base);
    const int i = i0 + th2, j = j0 + tj;
    if (h == 0) {
      if (j <= i) {
        atomicAdd(&out[(b * Ssz + i) * Ssz + j], v0);
        if (j < i) atomicAdd(&out[(b * Ssz + j) * Ssz + i], v0);
      }
      if (j <= i + 1) {
        atomicAdd(&out[(b * Ssz + i + 1) * Ssz + j], v1);
        if (j < i + 1) atomicAdd(&out[(b * Ssz + j) * Ssz + (i + 1)], v1);
      }
    } else {
      float* o = out + h * OUTMAT;
      atomicAdd(&o[(b * Ssz + i) * Ssz + j], v0);
      atomicAdd(&o[(b * Ssz + i + 1) * Ssz + j], v1);
    }
  }
}

extern "C" void kernel_launch(void* const* d_in, const int* in_sizes, int n_in,
                              void* d_out, int out_size, void* d_ws,
                              size_t ws_size, hipStream_t stream) {
  (void)in_sizes; (void)n_in; (void)out_size; (void)ws_size;
  const float* x = (const float*)d_in[0];
  K1Args a;
  a.W1[0] = (const float*)d_in[1];  a.b1[0] = (const float*)d_in[2];
  a.W1[1] = (const float*)d_in[5];  a.b1[1] = (const float*)d_in[6];
  a.W1[2] = (const float*)d_in[9];  a.b1[2] = (const float*)d_in[10];
  a.W1[3] = (const float*)d_in[13]; a.b1[3] = (const float*)d_in[14];
  const float* w2a = (const float*)d_in[3];
  const float* b2a = (const float*)d_in[4];
  const float* w2b = (const float*)d_in[7];
  const float* b2b = (const float*)d_in[8];
  const float* w2c = (const float*)d_in[11];
  const float* b2c = (const float*)d_in[12];
  const float* W2l = (const float*)d_in[15];
  const float* b2l = (const float*)d_in[16];
  float* out = (float*)d_out;

  // ws layout (ushorts): [0, 8*SLOT): 8 f16 ea-slots, all row-major [b][m][l].
  // Then W1F (4MB frag order), X16F (1MB), W2F (64KB), Sums (3 floats).
  unsigned short* U    = (unsigned short*)d_ws;
  unsigned short* W1F  = U + 8 * SLOT;
  unsigned short* X16F = U + 8 * SLOT + 4 * (Lsz * D2);
  unsigned short* W2F  = U + 8 * SLOT + 5 * (Lsz * D2);
  float* Sums = (float*)(W2F + 64 * Lsz);

  prep_all<<<dim3(43, 16, 6), 256, 0, stream>>>(
      x, a, W2l, w2a, w2b, w2c, b2a, b2b, b2c, W1F, X16F, W2F, Sums, out);
  gemm_lr_f16f<<<dim3(8, 16, 8), 256, 0, stream>>>(X16F, W1F, a, U);
  pair_fused<<<dim3(512, Bsz), 256, 0, stream>>>(
      U, W2F, b2l, w2a, w2b, w2c, Sums, out);
}

// Round 6
// 166.197 us; speedup vs baseline: 1.2973x; 1.2973x over previous
//
#include <hip/hip_runtime.h>

#define Bsz 8
#define Ssz 128
#define Dsz 512
#define D2 1024
#define Lsz 512
#define Rsz 50
#define SLOT 524288        // ushorts per slot (1 MB)
#define BSLOT 65536        // per-b stride in transposed slots (ushorts)
#define OUTMAT 131072

typedef __attribute__((ext_vector_type(8))) _Float16 f16x8;
typedef __attribute__((ext_vector_type(2))) __fp16 fp16x2;
typedef __attribute__((ext_vector_type(4))) float f32x4;

union UV4 { uint4 u; f16x8 h; };
union UH { unsigned short s; _Float16 h; };
union UP { fp16x2 h; unsigned u; };

struct K1Args {
  const float* W1[4];
  const float* b1[4];
};

__device__ __forceinline__ float f16lo(unsigned u) {
  UH x; x.s = (unsigned short)(u & 0xffffu); return (float)x.h;
}
__device__ __forceinline__ float f16hi(unsigned u) {
  UH x; x.s = (unsigned short)(u >> 16); return (float)x.h;
}
__device__ __forceinline__ float f16v(unsigned short s) {
  UH x; x.s = s; return (float)x.h;
}
__device__ __forceinline__ unsigned pkrtz(float a, float b) {
  UP c; c.h = __builtin_amdgcn_cvt_pkrtz(a, b); return c.u;
}
__device__ __forceinline__ unsigned short f2h(float v) {
  UH x; x.h = (_Float16)v; return x.s;
}
__device__ __forceinline__ float rcpf(float x) {
  return __builtin_amdgcn_rcpf(x);
}

// tanh pair (packed): 1 - 2*rcp(ea*eb + 1). f16 overflow -> inf -> rcp 0 is
// the correct tanh limit.
__device__ __forceinline__ unsigned tanh2u(unsigned ea, unsigned eb) {
  UP a, b, p; a.u = ea; b.u = eb;
  const fp16x2 one = {(__fp16)1.0f, (__fp16)1.0f};
  p.h = a.h * b.h + one;
  const float h0 = fmaf(-2.0f, rcpf((float)p.h.x), 1.0f);
  const float h1 = fmaf(-2.0f, rcpf((float)p.h.y), 1.0f);
  return pkrtz(h0, h1);
}

// ---------------------------------------------------------------------------
// Prep (merged): z<4: W1[z] -> W1F f16 fragment order.
// z==4: x -> X16F f16 fragment order.
// z==5: x<16: label W2 -> W2F fragment order; x 16..18: Sums[h] = sum(w2_h)
//        + b2_h[0] (for pair scalar path's S-trick).
// ---------------------------------------------------------------------------
__global__ __launch_bounds__(256) void prep_all(
    const float* __restrict__ x, K1Args a, const float* __restrict__ W2,
    const float* __restrict__ w2a, const float* __restrict__ w2b,
    const float* __restrict__ w2c,
    const float* __restrict__ b2a, const float* __restrict__ b2b,
    const float* __restrict__ b2c,
    unsigned short* __restrict__ W1F, unsigned short* __restrict__ X16F,
    unsigned short* __restrict__ W2F, float* __restrict__ Sums) {
  const int z = blockIdx.z;
  const int t = threadIdx.x;
  if (z < 4) {
    if (blockIdx.x >= 8) return;
    __shared__ float S[64][65];
    const float* __restrict__ W = a.W1[z];
    const int n0 = blockIdx.x * 64;
    const int k0 = blockIdx.y * 64;
    {
      const int kk = t >> 2, c16 = (t & 3) * 16;
      const float* p = W + (k0 + kk) * Lsz + n0 + c16;
#pragma unroll
      for (int c = 0; c < 4; ++c) {
        float4 v = *(const float4*)(p + c * 4);
        S[kk][c16 + c * 4 + 0] = v.x; S[kk][c16 + c * 4 + 1] = v.y;
        S[kk][c16 + c * 4 + 2] = v.z; S[kk][c16 + c * 4 + 3] = v.w;
      }
    }
    __syncthreads();
#pragma unroll
    for (int o = t; o < 512; o += 256) {
      const int lane = o & 63;
      const int ntl = (o >> 6) & 3, kbl = o >> 8;
      const int n_l = ntl * 16 + (lane & 15);
      const int k_l = kbl * 32 + (lane >> 4) * 8;
      uint4 pk;
      pk.x = pkrtz(S[k_l + 0][n_l], S[k_l + 1][n_l]);
      pk.y = pkrtz(S[k_l + 2][n_l], S[k_l + 3][n_l]);
      pk.z = pkrtz(S[k_l + 4][n_l], S[k_l + 5][n_l]);
      pk.w = pkrtz(S[k_l + 6][n_l], S[k_l + 7][n_l]);
      const long addr =
          ((long)((z * 32 + blockIdx.x * 4 + ntl) * 32 + blockIdx.y * 2 + kbl) *
               64 + lane) * 8;
      *(uint4*)(W1F + addr) = pk;
    }
  } else if (z == 4) {
    if (blockIdx.x >= 16) return;
    const int idx = (blockIdx.y * 16 + blockIdx.x) * 256 + t;  // [0,65536)
    const int frag = idx >> 6, lane = idx & 63;
    const int m = (frag >> 4) * 16 + (lane & 15);
    const int k0 = (frag & 15) * 32 + (lane >> 4) * 8;
    const float* p = x + m * Dsz + k0;
    float4 v0 = *(const float4*)p, v1 = *(const float4*)(p + 4);
    uint4 pk = make_uint4(pkrtz(v0.x, v0.y), pkrtz(v0.z, v0.w),
                          pkrtz(v1.x, v1.y), pkrtz(v1.z, v1.w));
    *(uint4*)(X16F + (long)idx * 8) = pk;
  } else {
    if (blockIdx.y != 0) return;
    if (blockIdx.x < 16) {
      const int idx = blockIdx.x * 256 + t;  // [0,4096)
      const int frag = idx >> 6, lane = idx & 63;
      const int o = (frag >> 4) * 16 + (lane & 15);
      const int k0 = (frag & 15) * 32 + (lane >> 4) * 8;
      float v[8];
#pragma unroll
      for (int e = 0; e < 8; ++e)
        v[e] = (o < Rsz) ? W2[(k0 + e) * Rsz + o] : 0.0f;
      uint4 pk = make_uint4(pkrtz(v[0], v[1]), pkrtz(v[2], v[3]),
                            pkrtz(v[4], v[5]), pkrtz(v[6], v[7]));
      *(uint4*)(W2F + (long)idx * 8) = pk;
    } else if (blockIdx.x < 19) {
      const int h = blockIdx.x - 16;
      const float* __restrict__ w2 = (h == 0) ? w2a : (h == 1 ? w2b : w2c);
      const float bb = (h == 0) ? b2a[0] : (h == 1 ? b2b[0] : b2c[0]);
      __shared__ float red[256];
      red[t] = w2[t] + w2[t + 256];
      __syncthreads();
      for (int s = 128; s > 0; s >>= 1) {
        if (t < s) red[t] += red[t + s];
        __syncthreads();
      }
      if (t == 0) Sums[h] = red[0] + bb;
    }
  }
}

// ---------------------------------------------------------------------------
// Kernel 1: projections, pure f16 MFMA, all K-loop loads coalesced (fragment
// order). Block 64m x 64n, wave 32x32, K=512 (side r = k-half of W1F).
// Epilogue: e = exp(2*(v + b1[left only])) stored f16:
//   scalar-head slots (h<3): transposed [b][l][i]; label slots 6,7: [m][l].
// ---------------------------------------------------------------------------
__global__ __launch_bounds__(256) void gemm_lr_f16f(
    const unsigned short* __restrict__ X16F,
    const unsigned short* __restrict__ W1F, K1Args a,
    unsigned short* __restrict__ U) {
  const int side = blockIdx.z;
  const int h = side >> 1, r = side & 1;
  const float* __restrict__ bias = a.b1[h];
  const int tid = threadIdx.x;
  const int w = tid >> 6, lane = tid & 63;
  const int lm = lane & 15, q = lane >> 4;
  const int mtb = blockIdx.y * 4 + (w & 1) * 2;   // m-tile base (of 16)
  const int ntb = blockIdx.x * 4 + (w >> 1) * 2;  // n-tile base

  f32x4 acc[2][2];
#pragma unroll
  for (int mt = 0; mt < 2; ++mt)
#pragma unroll
    for (int nt = 0; nt < 2; ++nt) {
      acc[mt][nt].x = 0.f; acc[mt][nt].y = 0.f;
      acc[mt][nt].z = 0.f; acc[mt][nt].w = 0.f;
    }

  for (int kb = 0; kb < 16; ++kb) {
    UV4 af[2], bf[2];
#pragma unroll
    for (int mt = 0; mt < 2; ++mt)
      af[mt].u = *(const uint4*)(X16F +
          ((long)((mtb + mt) * 16 + kb) * 64 + lane) * 8);
#pragma unroll
    for (int nt = 0; nt < 2; ++nt)
      bf[nt].u = *(const uint4*)(W1F +
          ((long)((h * 32 + ntb + nt) * 32 + r * 16 + kb) * 64 + lane) * 8);
#pragma unroll
    for (int mt = 0; mt < 2; ++mt)
#pragma unroll
      for (int nt = 0; nt < 2; ++nt)
        acc[mt][nt] = __builtin_amdgcn_mfma_f32_16x16x32_f16(
            af[mt].h, bf[nt].h, acc[mt][nt], 0, 0, 0);
  }

  unsigned short* slot = U + side * SLOT;
  if (h < 3) {
#pragma unroll
    for (int nt = 0; nt < 2; ++nt) {
      const int n_out = (ntb + nt) * 16 + lm;
      const float bb = (r == 0) ? bias[n_out] : 0.0f;
#pragma unroll
      for (int mt = 0; mt < 2; ++mt) {
        const int m0r = (mtb + mt) * 16 + q * 4;
        const float e0 = __expf(2.0f * (acc[mt][nt].x + bb));
        const float e1 = __expf(2.0f * (acc[mt][nt].y + bb));
        const float e2 = __expf(2.0f * (acc[mt][nt].z + bb));
        const float e3 = __expf(2.0f * (acc[mt][nt].w + bb));
        uint2 pr;
        pr.x = pkrtz(e0, e1);
        pr.y = pkrtz(e2, e3);
        const int bi = m0r >> 7, il = m0r & 127;
        *(uint2*)(slot + bi * BSLOT + n_out * Ssz + il) = pr;
      }
    }
  } else {
#pragma unroll
    for (int nt = 0; nt < 2; ++nt) {
      const int n_out = (ntb + nt) * 16 + lm;
      const float bb = (r == 0) ? bias[n_out] : 0.0f;
#pragma unroll
      for (int mt = 0; mt < 2; ++mt) {
#pragma unroll
        for (int reg = 0; reg < 4; ++reg) {
          const int m_out = (mtb + mt) * 16 + q * 4 + reg;
          float v;
          if (reg == 0) v = acc[mt][nt].x;
          else if (reg == 1) v = acc[mt][nt].y;
          else if (reg == 2) v = acc[mt][nt].z;
          else v = acc[mt][nt].w;
          slot[m_out * Lsz + n_out] = f2h(__expf(2.0f * (v + bb)));
        }
      }
    }
  }
}

// ---------------------------------------------------------------------------
// Fused pair kernel v6: R2's proven inner loops; scheduling change only.
// Grid x in [0,320) per b:
//   x < 192 -> scalar half-block: tile = x>>1 (96: h=tile>>5, it, jt),
//              lhalf = x&1 (256 l). R2's LDS-staged inner; writes raw
//              partial sums to P[lhalf] (no atomics). Launches FIRST
//              (long blocks), labels backfill.
//   x >= 192 -> label block, i = x-192, global-direct MFMA path.
// combine_sc then computes out = Sums - 2*(P0+P1) (+ span mirror).
// ---------------------------------------------------------------------------
__global__ __launch_bounds__(256) void pair_fused(
    const unsigned short* __restrict__ U,
    const unsigned short* __restrict__ W2F,
    const float* __restrict__ b2l,
    const float* __restrict__ w2a, const float* __restrict__ w2b,
    const float* __restrict__ w2c,
    float* __restrict__ P, float* __restrict__ out) {
  __shared__ unsigned short As[64][20];   // [l][i], pad keeps 8B align
  __shared__ unsigned short Bs[64][40];   // [l][j], pad keeps 16B align
  __shared__ float w2s[64];

  const int b = blockIdx.y;
  const int tid = threadIdx.x;

  if (blockIdx.x >= 192) {
    // ----------------------- label head (global-direct) -------------------
    const int i = blockIdx.x - 192;
    const int w = tid >> 6, lane = tid & 63;
    const int lm = lane & 15, q = lane >> 4;
    const int jb = w * 32;

    const unsigned short* __restrict__ Lrow =
        U + 6 * SLOT + (b * Ssz + i) * Lsz;
    const unsigned short* __restrict__ Rb0 = U + 7 * SLOT + (long)b * Ssz * Lsz;
    float* out3 = out + 3 * OUTMAT;

    const unsigned short* Lb = Lrow + q * 8;
    const unsigned short* R0 = Rb0 + (jb + lm) * Lsz + q * 8;        // mt=0
    const unsigned short* R1 = Rb0 + (jb + 16 + lm) * Lsz + q * 8;   // mt=1
    const unsigned short* Bb = W2F + lane * 8;

    f32x4 acc[2][4];
#pragma unroll
    for (int mt = 0; mt < 2; ++mt)
#pragma unroll
      for (int nt = 0; nt < 4; ++nt) {
        acc[mt][nt].x = 0.f; acc[mt][nt].y = 0.f;
        acc[mt][nt].z = 0.f; acc[mt][nt].w = 0.f;
      }

#pragma unroll 2
    for (int c = 0; c < 8; ++c) {
      const uint4 lf0 = *(const uint4*)(Lb + c * 64);
      const uint4 lf1 = *(const uint4*)(Lb + c * 64 + 32);
#pragma unroll
      for (int kbl = 0; kbl < 2; ++kbl) {
        const uint4 lf = kbl ? lf1 : lf0;
        UV4 bfr[4];
#pragma unroll
        for (int nt = 0; nt < 4; ++nt)
          bfr[nt].u =
              *(const uint4*)(Bb + (long)(nt * 16 + kbl + 2 * c) * 512);
#pragma unroll
        for (int mt = 0; mt < 2; ++mt) {
          const uint4 rv =
              *(const uint4*)((mt ? R1 : R0) + c * 64 + kbl * 32);
          UV4 A;
          A.u = make_uint4(tanh2u(lf.x, rv.x), tanh2u(lf.y, rv.y),
                           tanh2u(lf.z, rv.z), tanh2u(lf.w, rv.w));
#pragma unroll
          for (int nt = 0; nt < 4; ++nt)
            acc[mt][nt] = __builtin_amdgcn_mfma_f32_16x16x32_f16(
                A.h, bfr[nt].h, acc[mt][nt], 0, 0, 0);
        }
      }
    }

#pragma unroll
    for (int nt = 0; nt < 4; ++nt) {
      const int o = nt * 16 + lm;
      if (o >= Rsz) continue;
      const float bias = b2l[o];
#pragma unroll
      for (int mt = 0; mt < 2; ++mt) {
#pragma unroll
        for (int reg = 0; reg < 4; ++reg) {
          const int j = jb + mt * 16 + q * 4 + reg;
          const long base = ((long)((b * Ssz + i) * Ssz) + j) * Rsz;
          float v;
          if (reg == 0) v = acc[mt][nt].x;
          else if (reg == 1) v = acc[mt][nt].y;
          else if (reg == 2) v = acc[mt][nt].z;
          else v = acc[mt][nt].w;
          out3[base + o] = v + bias;
        }
      }
    }
  } else {
    // -------------------- scalar heads (R2 inner, l-half) -----------------
    const int tile = blockIdx.x >> 1;
    const int lhalf = blockIdx.x & 1;
    const int h = tile >> 5;
    const int r = tile & 31;
    const int it = r >> 2, jt = r & 3;
    const int i0 = it * 16, j0 = jt * 32;
    if (h == 0 && i0 + 15 < j0) return;   // span: tile fully above diagonal
    const int t = tid;
    const int tj = t & 31;        // j offset
    const int th = t >> 5;        // i-pair index 0..7 -> i = i0 + th*2
    const int lb = lhalf * 256;

    const unsigned short* __restrict__ A  = U + (2 * h) * SLOT + b * BSLOT;
    const unsigned short* __restrict__ Bt = U + (2 * h + 1) * SLOT + b * BSLOT;
    const float* __restrict__ w2 = (h == 0) ? w2a : (h == 1 ? w2b : w2c);

    float acc0 = 0.f, acc1 = 0.f;
    const int sr = t >> 2;         // 0..63 (l row)
    const int scA = (t & 3) * 4;   // 4 u16 per thread
    const int scB = (t & 3) * 8;   // 8 u16 per thread

    for (int lc = lb; lc < lb + 256; lc += 64) {
      __syncthreads();
      *(uint2*)&As[sr][scA] = *(const uint2*)(A + (lc + sr) * Ssz + i0 + scA);
      *(uint4*)&Bs[sr][scB] = *(const uint4*)(Bt + (lc + sr) * Ssz + j0 + scB);
      if (t < 64) w2s[t] = w2[lc + t];
      __syncthreads();
#pragma unroll 8
      for (int l = 0; l < 64; ++l) {
        const float wv = w2s[l];
        const unsigned ua = *(const unsigned*)&As[l][th * 2];
        const float a0 = f16lo(ua), a1 = f16hi(ua);
        const float bb = f16v(Bs[l][tj]);
        acc0 = fmaf(wv, rcpf(fmaf(a0, bb, 1.0f)), acc0);
        acc1 = fmaf(wv, rcpf(fmaf(a1, bb, 1.0f)), acc1);
      }
    }

    const int i = i0 + th * 2, j = j0 + tj;
    float* Ph = P + ((long)(lhalf * 3 + h) * Bsz + b) * 16384;
    Ph[i * Ssz + j] = acc0;
    Ph[(i + 1) * Ssz + j] = acc1;
  }
}

// ---------------------------------------------------------------------------
// Combine: out = Sums[h] - 2*(P0+P1); span head mirrors lower triangle.
// Grid (8 chunks, 8 b, 3 h), 256 thr, 8 elems/thread. L2-hot, ~3 us.
// ---------------------------------------------------------------------------
__global__ __launch_bounds__(256) void combine_sc(
    const float* __restrict__ P, const float* __restrict__ Sums,
    float* __restrict__ out) {
  const int ck = blockIdx.x, b = blockIdx.y, h = blockIdx.z;
  const int t = threadIdx.x;
  const float Sh = Sums[h];
  const float* P0 = P + ((long)(0 * 3 + h) * Bsz + b) * 16384;
  const float* P1 = P + ((long)(1 * 3 + h) * Bsz + b) * 16384;
  if (h == 0) {
#pragma unroll
    for (int k = 0; k < 8; ++k) {
      const int idx = ck * 2048 + k * 256 + t;
      const int i = idx >> 7, j = idx & 127;
      if (j > i) continue;
      const float v = fmaf(-2.0f, P0[idx] + P1[idx], Sh);
      out[(b * Ssz + i) * Ssz + j] = v;
      out[(b * Ssz + j) * Ssz + i] = v;
    }
  } else {
    float* o = out + h * OUTMAT + b * 16384;
#pragma unroll
    for (int k = 0; k < 8; ++k) {
      const int idx = ck * 2048 + k * 256 + t;
      o[idx] = fmaf(-2.0f, P0[idx] + P1[idx], Sh);
    }
  }
}

extern "C" void kernel_launch(void* const* d_in, const int* in_sizes, int n_in,
                              void* d_out, int out_size, void* d_ws,
                              size_t ws_size, hipStream_t stream) {
  (void)in_sizes; (void)n_in; (void)out_size; (void)ws_size;
  const float* x = (const float*)d_in[0];
  K1Args a;
  a.W1[0] = (const float*)d_in[1];  a.b1[0] = (const float*)d_in[2];
  a.W1[1] = (const float*)d_in[5];  a.b1[1] = (const float*)d_in[6];
  a.W1[2] = (const float*)d_in[9];  a.b1[2] = (const float*)d_in[10];
  a.W1[3] = (const float*)d_in[13]; a.b1[3] = (const float*)d_in[14];
  const float* w2a = (const float*)d_in[3];
  const float* b2a = (const float*)d_in[4];
  const float* w2b = (const float*)d_in[7];
  const float* b2b = (const float*)d_in[8];
  const float* w2c = (const float*)d_in[11];
  const float* b2c = (const float*)d_in[12];
  const float* W2l = (const float*)d_in[15];
  const float* b2l = (const float*)d_in[16];
  float* out = (float*)d_out;

  // ws layout (ushorts): [0, 8*SLOT): 8 f16 ea-slots (scalar heads transposed
  // [b][l][i]; label 6,7 row-major [m][l]). Then W1F (4MB frag order),
  // X16F (1MB), W2F (64KB), Sums (3 floats + pad), P (2x3x8x16384 floats).
  unsigned short* U    = (unsigned short*)d_ws;
  unsigned short* W1F  = U + 8 * SLOT;
  unsigned short* X16F = U + 8 * SLOT + 4 * (Lsz * D2);
  unsigned short* W2F  = U + 8 * SLOT + 5 * (Lsz * D2);
  float* Sums = (float*)(W2F + 64 * Lsz);
  float* P = Sums + 4;

  prep_all<<<dim3(19, 16, 6), 256, 0, stream>>>(
      x, a, W2l, w2a, w2b, w2c, b2a, b2b, b2c, W1F, X16F, W2F, Sums);
  gemm_lr_f16f<<<dim3(8, 16, 8), 256, 0, stream>>>(X16F, W1F, a, U);
  pair_fused<<<dim3(320, Bsz), 256, 0, stream>>>(
      U, W2F, b2l, w2a, w2b, w2c, P, out);
  combine_sc<<<dim3(8, Bsz, 3), 256, 0, stream>>>(P, Sums, out);
}